// Round 6
// baseline (780.415 us; speedup 1.0000x reference)
//
#include <hip/hip_runtime.h>
#include <cmath>

static constexpr int NN  = 50000;   // nodes
static constexpr int NE  = 800000;  // edges
static constexpr int HID = 64;
static constexpr int BB  = 64;      // batch
static constexpr int TT  = 200;     // seq len
static constexpr int LH  = 128;     // lstm hidden
static constexpr int G4  = 512;     // 4*LH

static constexpr int SCB = 125;     // scan blocks
static constexpr int SCH = 400;     // elems per scan block (125*400 = 50000)

typedef _Float16 h2 __attribute__((ext_vector_type(2)));

#ifndef __has_builtin
#define __has_builtin(x) 0
#endif
#if __has_builtin(__builtin_amdgcn_fdot2)
__device__ __forceinline__ float fdot2_(h2 a, h2 b, float c) {
    return __builtin_amdgcn_fdot2(a, b, c, false);
}
#else
__device__ __forceinline__ float fdot2_(h2 a, h2 b, float c) {
    return c + (float)a.x * (float)b.x + (float)a.y * (float)b.y;
}
#endif

__device__ __forceinline__ h2 as_h2(unsigned int u) {
    union { unsigned int u; h2 h; } cv; cv.u = u; return cv.h;
}
__device__ __forceinline__ unsigned int as_u32(h2 h) {
    union { h2 h; unsigned int u; } cv; cv.h = h; return cv.u;
}

__device__ __forceinline__ float tanh_fast(float x) {
    return __fdividef(2.f, 1.f + __expf(-2.f * x)) - 1.f;
}

// ================= CSR build =================
__global__ __launch_bounds__(256) void hist_kernel(const int* __restrict__ dsts,
                                                   int* __restrict__ deg) {
    int i = blockIdx.x * 256 + threadIdx.x;
    if (i < NE) atomicAdd(&deg[dsts[i]], 1);
}

__global__ __launch_bounds__(512) void scan1_kernel(const int* __restrict__ deg,
                                                    int* __restrict__ loc,
                                                    int* __restrict__ bsum) {
    __shared__ int ws[8];
    const int b = blockIdx.x, t = threadIdx.x;
    const int idx = b * SCH + t;
    const int lane = t & 63, wv = t >> 6;
    int v = (t < SCH && idx < NN) ? deg[idx] : 0;
    int x = v;
    #pragma unroll
    for (int off = 1; off < 64; off <<= 1) {
        int y = __shfl_up(x, off);
        if (lane >= off) x += y;
    }
    if (lane == 63) ws[wv] = x;
    __syncthreads();
    if (t < 8) {
        int s = ws[t];
        #pragma unroll
        for (int off = 1; off < 8; off <<= 1) {
            int y = __shfl_up(s, off);
            if (t >= off) s += y;
        }
        ws[t] = s;
    }
    __syncthreads();
    const int base = wv ? ws[wv - 1] : 0;
    if (t < SCH && idx < NN) loc[idx] = base + x - v;
    if (t == 511) bsum[b] = ws[7];
}

__global__ void scan2_kernel(const int* __restrict__ bsum,
                             int* __restrict__ boff,
                             int* __restrict__ rowptr) {
    int tot = 0;
    for (int i = 0; i < SCB; ++i) { boff[i] = tot; tot += bsum[i]; }
    rowptr[NN] = tot;
}

__global__ __launch_bounds__(512) void scan3_kernel(const int* __restrict__ loc,
                                                    const int* __restrict__ boff,
                                                    int* __restrict__ rowptr,
                                                    int* __restrict__ head) {
    const int b = blockIdx.x, t = threadIdx.x;
    const int idx = b * SCH + t;
    if (t < SCH && idx < NN) {
        int r = loc[idx] + boff[b];
        rowptr[idx] = r;
        head[idx] = r;
    }
}

__global__ __launch_bounds__(256) void scatter_kernel(const int* __restrict__ srcs,
                                                      const int* __restrict__ dsts,
                                                      int* __restrict__ head,
                                                      int* __restrict__ perm,
                                                      int* __restrict__ ssrc) {
    int e = blockIdx.x * 256 + threadIdx.x;
    if (e < NE) {
        int d = dsts[e];
        int pos = atomicAdd(&head[d], 1);
        perm[e] = pos;
        ssrc[pos] = srcs[e];
    }
}

// permute edge_attr into dst-sorted order, fp32 -> fp16 (one-time, shared by both layers)
__global__ __launch_bounds__(256) void permute_kernel(const float* __restrict__ ea,
                                                      const int* __restrict__ perm,
                                                      ushort4* __restrict__ easort) {
    const int lane = threadIdx.x & 63, wid = threadIdx.x >> 6;
    const int slot = lane >> 4, hw = lane & 15;
    const int e = (blockIdx.x * 4 + wid) * 4 + slot;
    if (e < NE) {
        const int p = perm[e];
        float4 v = ((const float4*)ea)[(size_t)e * 16 + hw];
        union { _Float16 h[4]; ushort4 u; } pk;
        pk.h[0] = (_Float16)v.x; pk.h[1] = (_Float16)v.y;
        pk.h[2] = (_Float16)v.z; pk.h[3] = (_Float16)v.w;
        easort[(size_t)p * 16 + hw] = pk.u;
    }
}

// fp32 -> fp16 convert (x table for layer-0 gathers), 4 elems/thread
__global__ __launch_bounds__(256) void cvt16_kernel(const float* __restrict__ in,
                                                    _Float16* __restrict__ o) {
    int i = blockIdx.x * 256 + threadIdx.x;   // i indexes groups of 4
    float4 v = ((const float4*)in)[i];
    union { _Float16 h[4]; ushort4 u; } pk;
    pk.h[0] = (_Float16)v.x; pk.h[1] = (_Float16)v.y;
    pk.h[2] = (_Float16)v.z; pk.h[3] = (_Float16)v.w;
    ((ushort4*)o)[i] = pk.u;
}

// ========= fused edge pass: CSR by dst, coalesced fp16 reads + fp16 h gather =========
__global__ __launch_bounds__(256) void edge_agg_kernel(
    const _Float16* __restrict__ h16,    // [NN][64] fp16 gather table
    const ushort4*  __restrict__ easort, // [NE][16] (64 halfs per edge, dst-sorted)
    const float*    __restrict__ W,      // [64][64] W[c][k]
    const float*    __restrict__ bias,   // [64]
    const int*      __restrict__ rowptr,
    const int*      __restrict__ ssrc,   // src per sorted pos
    float*          __restrict__ agg)
{
    __shared__ ushort4 stage[4][64];     // per wave: 4 edges x 64 halfs
    const int lane = threadIdx.x & 63;
    const int wid  = threadIdx.x >> 6;
    const int slot = lane >> 4, hw = lane & 15;

    h2 w2[32];
    {
        const float4* wf = (const float4*)(W + lane * 64);
        #pragma unroll
        for (int k4 = 0; k4 < 16; ++k4) {
            float4 v = wf[k4];
            h2 a; a.x = (_Float16)v.x; a.y = (_Float16)v.y;
            h2 b; b.x = (_Float16)v.z; b.y = (_Float16)v.w;
            w2[2*k4] = a; w2[2*k4+1] = b;
        }
    }
    const float bc = bias[lane];

    const int gw = blockIdx.x * 4 + wid;
    const int nw = gridDim.x * 4;
    for (int n = gw; n < NN; n += nw) {
        const int ofs = rowptr[n];
        const int dg  = rowptr[n + 1] - ofs;
        float acc = 0.f;
        for (int c = 0; c < dg; c += 4) {
            const int rem = dg - c;
            const int pick = slot < rem ? slot : rem - 1;
            const int ssv = ssrc[ofs + c + pick];
            stage[wid][lane] = easort[(size_t)(ofs + c + pick) * 16 + hw];
            if (rem >= 4) {
                float hv[4];
                #pragma unroll
                for (int j = 0; j < 4; ++j) {
                    int sj = __shfl(ssv, j << 4);
                    hv[j] = (float)h16[(size_t)sj * HID + lane];
                }
                asm volatile("s_waitcnt lgkmcnt(0)" ::: "memory");
                #pragma unroll
                for (int j = 0; j < 4; ++j) {
                    const uint4* stu = (const uint4*)&stage[wid][j * 16];
                    float aE = bc;
                    #pragma unroll
                    for (int k = 0; k < 8; ++k) {
                        uint4 u = stu[k];
                        aE = fdot2_(as_h2(u.x), w2[4*k+0], aE);
                        aE = fdot2_(as_h2(u.y), w2[4*k+1], aE);
                        aE = fdot2_(as_h2(u.z), w2[4*k+2], aE);
                        aE = fdot2_(as_h2(u.w), w2[4*k+3], aE);
                    }
                    float m = aE + hv[j];
                    acc += m > 0.f ? m : 0.f;
                }
            } else {
                asm volatile("s_waitcnt lgkmcnt(0)" ::: "memory");
                for (int j = 0; j < rem; ++j) {
                    int sj = __shfl(ssv, j << 4);
                    const uint4* stu = (const uint4*)&stage[wid][j * 16];
                    float aE = bc;
                    #pragma unroll
                    for (int k = 0; k < 8; ++k) {
                        uint4 u = stu[k];
                        aE = fdot2_(as_h2(u.x), w2[4*k+0], aE);
                        aE = fdot2_(as_h2(u.y), w2[4*k+1], aE);
                        aE = fdot2_(as_h2(u.z), w2[4*k+2], aE);
                        aE = fdot2_(as_h2(u.w), w2[4*k+3], aE);
                    }
                    float m = aE + (float)h16[(size_t)sj * HID + lane];
                    acc += m > 0.f ? m : 0.f;
                }
            }
        }
        agg[(size_t)n * HID + lane] = acc;
    }
}

// ---------------- node pass (also emits fp16 copy of h_out for next gather) ----------------
__global__ __launch_bounds__(256) void node_kernel(
    const float* __restrict__ h_in,
    const float* __restrict__ agg,
    const float* __restrict__ W1, const float* __restrict__ b1,
    const float* __restrict__ W2, const float* __restrict__ b2,
    const float* __restrict__ epsp,
    const float* __restrict__ lnS, const float* __restrict__ lnB,
    float*       __restrict__ h_out,
    _Float16*    __restrict__ h16_out)   // may be null
{
    __shared__ float zbuf[4][64];
    __shared__ float tbuf[4][64];
    const int lane = threadIdx.x & 63;
    const int wid  = threadIdx.x >> 6;

    float w1[64], w2[64];
    {
        const float4* wf1 = (const float4*)(W1 + lane * 64);
        const float4* wf2 = (const float4*)(W2 + lane * 64);
        #pragma unroll
        for (int k4 = 0; k4 < 16; ++k4) {
            float4 a = wf1[k4], b = wf2[k4];
            w1[4*k4+0]=a.x; w1[4*k4+1]=a.y; w1[4*k4+2]=a.z; w1[4*k4+3]=a.w;
            w2[4*k4+0]=b.x; w2[4*k4+1]=b.y; w2[4*k4+2]=b.z; w2[4*k4+3]=b.w;
        }
    }
    const float b1c = b1[lane], b2c = b2[lane];
    const float sC = lnS[lane], bC = lnB[lane];
    const float epv = 1.f + epsp[0];

    const int gw = blockIdx.x * 4 + wid;
    const int nw = gridDim.x * 4;
    for (int n = gw; n < NN; n += nw) {
        float z = epv * h_in[(size_t)n*HID + lane] + agg[(size_t)n*HID + lane];
        zbuf[wid][lane] = z;
        asm volatile("s_waitcnt lgkmcnt(0)" ::: "memory");
        float acc = b1c;
        {
            const float4* zf = (const float4*)&zbuf[wid][0];
            #pragma unroll
            for (int k4 = 0; k4 < 16; ++k4) {
                float4 v = zf[k4];
                acc = fmaf(v.x, w1[4*k4+0], acc);
                acc = fmaf(v.y, w1[4*k4+1], acc);
                acc = fmaf(v.z, w1[4*k4+2], acc);
                acc = fmaf(v.w, w1[4*k4+3], acc);
            }
        }
        acc = acc > 0.f ? acc : 0.f;
        tbuf[wid][lane] = acc;
        asm volatile("s_waitcnt lgkmcnt(0)" ::: "memory");
        float acc2 = b2c;
        {
            const float4* tf = (const float4*)&tbuf[wid][0];
            #pragma unroll
            for (int k4 = 0; k4 < 16; ++k4) {
                float4 v = tf[k4];
                acc2 = fmaf(v.x, w2[4*k4+0], acc2);
                acc2 = fmaf(v.y, w2[4*k4+1], acc2);
                acc2 = fmaf(v.z, w2[4*k4+2], acc2);
                acc2 = fmaf(v.w, w2[4*k4+3], acc2);
            }
        }
        float s1 = acc2, s2 = acc2 * acc2;
        #pragma unroll
        for (int off = 32; off >= 1; off >>= 1) {
            s1 += __shfl_xor(s1, off);
            s2 += __shfl_xor(s2, off);
        }
        float mu  = s1 * (1.f/64.f);
        float var = s2 * (1.f/64.f) - mu * mu;
        float r   = rsqrtf(var + 1e-5f);
        float o   = (acc2 - mu) * r * sC + bC;
        float ov  = o > 0.f ? o : 0.f;
        h_out[(size_t)n*HID + lane] = ov;
        if (h16_out) h16_out[(size_t)n*HID + lane] = (_Float16)ov;
    }
}

// ---------------- prep: W2T transpose + selp = b_ih + sel @ W_ih[:, :64]^T ----------------
// outputs stored PERMUTED to lstm thread order: thread t <- gate (t&3)*128 + (t>>2)
__global__ __launch_bounds__(512) void prep_kernel(
    const float* __restrict__ Wih,   // [512][96]
    const float* __restrict__ bih,   // [512]
    const float* __restrict__ h2v,   // [NN][64]
    const int*   __restrict__ nidx,  // [64]
    float*       __restrict__ W2T,   // [32][512] permuted cols
    float*       __restrict__ selp)  // [64][512] permuted cols
{
    const int g = threadIdx.x;                        // gate index 0..511
    const int pos = ((g & 127) << 2) | (g >> 7);      // lstm thread owning gate g
    if (blockIdx.x == BB) {
        #pragma unroll
        for (int k = 0; k < 32; ++k)
            W2T[k * G4 + pos] = Wih[g * 96 + 64 + k];
    } else {
        const int b = blockIdx.x;
        __shared__ float hrow[64];
        if (g < 64) hrow[g] = h2v[(size_t)nidx[b] * HID + g];
        __syncthreads();
        float acc = bih[g];
        #pragma unroll
        for (int k = 0; k < 64; ++k)
            acc = fmaf(hrow[k], Wih[g * 96 + k], acc);
        selp[b * G4 + pos] = acc;
    }
}

// ---------------- xp[t][b][tid] = selp[b][tid] + x_seq[b][t] @ W2T[:,tid] ----------------
__global__ __launch_bounds__(512) void xp_kernel(
    const float* __restrict__ xseq,  // [B][T][32]
    const float* __restrict__ selp,  // [B][512] permuted
    const float* __restrict__ W2T,   // [32][512] permuted
    float*       __restrict__ xp)    // [T][B][512] permuted
{
    const int g   = threadIdx.x;
    const int row = blockIdx.x;      // row = t*64 + b
    const int t   = row >> 6;
    const int b   = row & 63;
    __shared__ float xs[32];
    if (g < 32) xs[g] = xseq[((size_t)b * TT + t) * 32 + g];
    __syncthreads();
    float acc = selp[b * G4 + g];
    #pragma unroll
    for (int k = 0; k < 32; ++k)
        acc = fmaf(xs[k], W2T[k * G4 + g], acc);
    xp[(size_t)row * G4 + g] = acc;
}

// ---------------- LSTM recurrence + final LN + fc ----------------
// TWO batch rows per block (1024 thr = 16 waves, 4/SIMD) so barrier stalls of one
// row are filled by the other row's issue. Per row: thread tid owns gate type
// gt=tid&3 of hidden unit j=tid>>2; gates exchanged via 3 shfl_xor; c replicated;
// ONE barrier/step (double-buffered packed-fp16 h); Whh fp16 in 64 VGPRs (dot2).
__global__ __launch_bounds__(1024) void lstm_kernel(
    const float* __restrict__ xp,    // [T][B][512] thread-order
    const float* __restrict__ Whh,   // [512][128]
    const float* __restrict__ bhh,   // [512]
    const float* __restrict__ lnS, const float* __restrict__ lnB,  // [128]
    const float* __restrict__ fcW,   // [1][128]
    const float* __restrict__ fcb,   // [1]
    float*       __restrict__ out)   // [64]
{
    const int tt = threadIdx.x;
    const int r  = tt >> 9;          // row within block (0/1)
    const int t  = tt & 511;
    const int b  = blockIdx.x * 2 + r;
    const int gt = t & 3;
    const int j  = t >> 2;
    const int gate = gt * LH + j;

    h2 w2[64];
    {
        const float4* wf = (const float4*)(Whh + (size_t)gate * LH);
        #pragma unroll
        for (int k4 = 0; k4 < 32; ++k4) {
            float4 v = wf[k4];
            h2 a; a.x = (_Float16)v.x; a.y = (_Float16)v.y;
            h2 c2; c2.x = (_Float16)v.z; c2.y = (_Float16)v.w;
            w2[2*k4] = a; w2[2*k4+1] = c2;
        }
    }
    const float bg = bhh[gate];
    const float s_ = (gt == 2) ? 2.f : 1.f;
    const float a_ = (gt == 2) ? 2.f : 1.f;
    const float d_ = (gt == 2) ? -1.f : 0.f;

    __shared__ unsigned int h2b0[2][64];
    __shared__ unsigned int h2b1[2][64];
    __shared__ float h_final[2][LH];
    if (t < 64) h2b0[r][t] = 0u;
    float c = 0.f;
    __syncthreads();

    float xv = xp[(size_t)b * G4 + t];    // t=0 slice

    auto step = [&](const unsigned int* hb, unsigned int* hw, int ts) {
        const int tn = (ts + 1 < TT) ? ts + 1 : ts;
        const float xv_next = xp[((size_t)tn * BB + b) * G4 + t];

        float a0 = 0.f, a1 = 0.f, a2 = 0.f, a3 = 0.f;
        const uint4* hb4 = (const uint4*)hb;
        #pragma unroll
        for (int k = 0; k < 16; k += 4) {
            uint4 u0 = hb4[k], u1 = hb4[k+1], u2 = hb4[k+2], u3 = hb4[k+3];
            a0 = fdot2_(as_h2(u0.x), w2[4*k+ 0], a0);
            a0 = fdot2_(as_h2(u0.y), w2[4*k+ 1], a0);
            a0 = fdot2_(as_h2(u0.z), w2[4*k+ 2], a0);
            a0 = fdot2_(as_h2(u0.w), w2[4*k+ 3], a0);
            a1 = fdot2_(as_h2(u1.x), w2[4*k+ 4], a1);
            a1 = fdot2_(as_h2(u1.y), w2[4*k+ 5], a1);
            a1 = fdot2_(as_h2(u1.z), w2[4*k+ 6], a1);
            a1 = fdot2_(as_h2(u1.w), w2[4*k+ 7], a1);
            a2 = fdot2_(as_h2(u2.x), w2[4*k+ 8], a2);
            a2 = fdot2_(as_h2(u2.y), w2[4*k+ 9], a2);
            a2 = fdot2_(as_h2(u2.z), w2[4*k+10], a2);
            a2 = fdot2_(as_h2(u2.w), w2[4*k+11], a2);
            a3 = fdot2_(as_h2(u3.x), w2[4*k+12], a3);
            a3 = fdot2_(as_h2(u3.y), w2[4*k+13], a3);
            a3 = fdot2_(as_h2(u3.z), w2[4*k+14], a3);
            a3 = fdot2_(as_h2(u3.w), w2[4*k+15], a3);
        }
        float acc = xv + bg + ((a0 + a1) + (a2 + a3));

        float act = fmaf(a_, __fdividef(1.f, 1.f + __expf(-s_ * acc)), d_);

        float v0 = act;
        float v1 = __shfl_xor(v0, 1);
        float v2 = __shfl_xor(v0, 2);
        float v3 = __shfl_xor(v1, 2);
        float iv = (gt==0)?v0:(gt==1)?v1:(gt==2)?v2:v3;
        float fv = (gt==1)?v0:(gt==0)?v1:(gt==3)?v2:v3;
        float gv = (gt==2)?v0:(gt==3)?v1:(gt==0)?v2:v3;
        float ov = (gt==3)?v0:(gt==2)?v1:(gt==1)?v2:v3;

        c = fmaf(fv, c, iv * gv);
        float hval = ov * tanh_fast(c);

        float hpart = __shfl_xor(hval, 4);
        if ((t & 7) == 0) {
            h2 p; p.x = (_Float16)hval; p.y = (_Float16)hpart;
            hw[j >> 1] = as_u32(p);
        }
        if (gt == 0) h_final[r][j] = hval;
        __syncthreads();

        xv = xv_next;
    };

    for (int ts = 0; ts < TT; ts += 2) {
        step(&h2b0[r][0], &h2b1[r][0], ts);
        step(&h2b1[r][0], &h2b0[r][0], ts + 1);
    }

    // epilogue: layernorm over h (128) + fc -> out[b]   (one wave per row does it)
    if (t < 64) {
        float h0 = h_final[r][t], h1 = h_final[r][t + 64];
        float s1 = h0 + h1, s2 = h0*h0 + h1*h1;
        #pragma unroll
        for (int off = 32; off >= 1; off >>= 1) {
            s1 += __shfl_xor(s1, off);
            s2 += __shfl_xor(s2, off);
        }
        float mu  = s1 * (1.f/128.f);
        float var = s2 * (1.f/128.f) - mu * mu;
        float rr  = rsqrtf(var + 1e-5f);
        float p = ((h0 - mu)*rr*lnS[t]      + lnB[t])      * fcW[t]
                + ((h1 - mu)*rr*lnS[t + 64] + lnB[t + 64]) * fcW[t + 64];
        #pragma unroll
        for (int off = 32; off >= 1; off >>= 1) p += __shfl_xor(p, off);
        if (t == 0) out[b] = p + fcb[0];
    }
}

extern "C" void kernel_launch(void* const* d_in, const int* in_sizes, int n_in,
                              void* d_out, int out_size, void* d_ws, size_t ws_size,
                              hipStream_t stream) {
    const float* x     = (const float*)d_in[0];
    const float* ea    = (const float*)d_in[1];
    const float* xseq  = (const float*)d_in[2];
    const float* linW  = (const float*)d_in[3];
    const float* linB  = (const float*)d_in[4];
    const float* mW1   = (const float*)d_in[5];
    const float* mb1   = (const float*)d_in[6];
    const float* mW2   = (const float*)d_in[7];
    const float* mb2   = (const float*)d_in[8];
    const float* eps   = (const float*)d_in[9];
    const float* lnS   = (const float*)d_in[10];
    const float* lnB   = (const float*)d_in[11];
    const float* Wih   = (const float*)d_in[12];
    const float* Whh   = (const float*)d_in[13];
    const float* bih   = (const float*)d_in[14];
    const float* bhh   = (const float*)d_in[15];
    const float* llnS  = (const float*)d_in[16];
    const float* llnB  = (const float*)d_in[17];
    const float* fcW   = (const float*)d_in[18];
    const float* fcb   = (const float*)d_in[19];
    const int*   eidx  = (const int*)d_in[20];
    const int*   nidx  = (const int*)d_in[21];
    float* out = (float*)d_out;

    const int* srcs = eidx;
    const int* dsts = eidx + NE;

    // workspace layout
    float* ws   = (float*)d_ws;
    float* agg  = ws;                              // NN*64
    float* h1   = agg  + (size_t)NN * HID;
    float* h2m  = h1   + (size_t)NN * HID;
    float* selp = h2m  + (size_t)NN * HID;         // BB*G4
    float* W2T  = selp + (size_t)BB * G4;          // 32*G4
    float* xp   = W2T  + (size_t)32 * G4;          // TT*BB*G4
    int*   deg    = (int*)(xp + (size_t)TT * BB * G4);  // NN
    int*   rowptr = deg + NN;                      // NN+1
    int*   head   = rowptr + NN + 2;               // NN
    int*   loc    = head + NN;                     // NN
    int*   bsum   = loc + NN;                      // SCB
    int*   boff   = bsum + SCB + 3;                // SCB
    int*   perm   = boff + SCB + 3;                // NE
    int*   ssrc   = perm + NE;                     // NE
    uintptr_t ep = (uintptr_t)(ssrc + NE);
    ep = (ep + 15) & ~(uintptr_t)15;
    ushort4* easort = (ushort4*)ep;                // NE*16 ushort4 = 102.4 MB
    _Float16* x16   = (_Float16*)(easort + (size_t)NE * 16);  // NN*64 halfs
    _Float16* h1_16 = x16 + (size_t)NN * HID;                 // NN*64 halfs

    // ---- CSR build + ea permute + x fp16 (shared by both layers) ----
    hipMemsetAsync(deg, 0, (size_t)NN * sizeof(int), stream);
    hist_kernel<<<(NE + 255) / 256, 256, 0, stream>>>(dsts, deg);
    scan1_kernel<<<SCB, 512, 0, stream>>>(deg, loc, bsum);
    scan2_kernel<<<1, 1, 0, stream>>>(bsum, boff, rowptr);
    scan3_kernel<<<SCB, 512, 0, stream>>>(loc, boff, rowptr, head);
    scatter_kernel<<<(NE + 255) / 256, 256, 0, stream>>>(srcs, dsts, head, perm, ssrc);
    permute_kernel<<<NE / 16, 256, 0, stream>>>(ea, perm, easort);
    cvt16_kernel<<<(NN * HID / 4 + 255) / 256, 256, 0, stream>>>(x, x16);

    // ---- layer 0 ----
    edge_agg_kernel<<<2048, 256, 0, stream>>>(x16, easort, linW, linB, rowptr, ssrc, agg);
    node_kernel<<<512, 256, 0, stream>>>(x, agg, mW1, mb1, mW2, mb2, eps, lnS, lnB, h1, h1_16);
    // ---- layer 1 ----
    edge_agg_kernel<<<2048, 256, 0, stream>>>(h1_16, easort, linW + 64*64, linB + 64, rowptr, ssrc, agg);
    node_kernel<<<512, 256, 0, stream>>>(h1, agg, mW1 + 64*64, mb1 + 64, mW2 + 64*64, mb2 + 64,
                                         eps + 1, lnS + 64, lnB + 64, h2m, (_Float16*)nullptr);
    // ---- LSTM input projection (permuted to lstm thread order) ----
    prep_kernel<<<BB + 1, 512, 0, stream>>>(Wih, bih, h2m, nidx, W2T, selp);
    xp_kernel<<<TT * BB, 512, 0, stream>>>(xseq, selp, W2T, xp);
    // ---- LSTM recurrence + head (2 batch rows per block) ----
    lstm_kernel<<<BB / 2, 1024, 0, stream>>>(xp, Whh, bhh, llnS, llnB, fcW, fcb, out);
}

// Round 7
// 687.411 us; speedup vs baseline: 1.1353x; 1.1353x over previous
//
#include <hip/hip_runtime.h>
#include <cmath>

static constexpr int NN  = 50000;   // nodes
static constexpr int NE  = 800000;  // edges
static constexpr int HID = 64;
static constexpr int BB  = 64;      // batch
static constexpr int TT  = 200;     // seq len
static constexpr int LH  = 128;     // lstm hidden
static constexpr int G4  = 512;     // 4*LH

static constexpr int SCB = 125;     // scan blocks
static constexpr int SCH = 400;     // elems per scan block (125*400 = 50000)

typedef _Float16 h2 __attribute__((ext_vector_type(2)));

#ifndef __has_builtin
#define __has_builtin(x) 0
#endif
#if __has_builtin(__builtin_amdgcn_fdot2)
__device__ __forceinline__ float fdot2_(h2 a, h2 b, float c) {
    return __builtin_amdgcn_fdot2(a, b, c, false);
}
#else
__device__ __forceinline__ float fdot2_(h2 a, h2 b, float c) {
    return c + (float)a.x * (float)b.x + (float)a.y * (float)b.y;
}
#endif

__device__ __forceinline__ h2 as_h2(unsigned int u) {
    union { unsigned int u; h2 h; } cv; cv.u = u; return cv.h;
}
__device__ __forceinline__ unsigned int as_u32(h2 h) {
    union { h2 h; unsigned int u; } cv; cv.h = h; return cv.u;
}

// DPP quad-perm move (VALU cross-lane, no DS pipe). 0xB1 = lane^1, 0x4E = lane^2.
template<int CTRL>
__device__ __forceinline__ float dpp_mov(float x) {
    union { float f; int i; } a, r;
    a.f = x;
    r.i = __builtin_amdgcn_mov_dpp(a.i, CTRL, 0xF, 0xF, true);
    return r.f;
}

__device__ __forceinline__ float tanh_fast(float x) {
    return __fdividef(2.f, 1.f + __expf(-2.f * x)) - 1.f;
}

// ================= CSR build =================
__global__ __launch_bounds__(256) void hist_kernel(const int* __restrict__ dsts,
                                                   int* __restrict__ deg) {
    int i = blockIdx.x * 256 + threadIdx.x;
    if (i < NE) atomicAdd(&deg[dsts[i]], 1);
}

__global__ __launch_bounds__(512) void scan1_kernel(const int* __restrict__ deg,
                                                    int* __restrict__ loc,
                                                    int* __restrict__ bsum) {
    __shared__ int ws[8];
    const int b = blockIdx.x, t = threadIdx.x;
    const int idx = b * SCH + t;
    const int lane = t & 63, wv = t >> 6;
    int v = (t < SCH && idx < NN) ? deg[idx] : 0;
    int x = v;
    #pragma unroll
    for (int off = 1; off < 64; off <<= 1) {
        int y = __shfl_up(x, off);
        if (lane >= off) x += y;
    }
    if (lane == 63) ws[wv] = x;
    __syncthreads();
    if (t < 8) {
        int s = ws[t];
        #pragma unroll
        for (int off = 1; off < 8; off <<= 1) {
            int y = __shfl_up(s, off);
            if (t >= off) s += y;
        }
        ws[t] = s;
    }
    __syncthreads();
    const int base = wv ? ws[wv - 1] : 0;
    if (t < SCH && idx < NN) loc[idx] = base + x - v;
    if (t == 511) bsum[b] = ws[7];
}

__global__ void scan2_kernel(const int* __restrict__ bsum,
                             int* __restrict__ boff,
                             int* __restrict__ rowptr) {
    int tot = 0;
    for (int i = 0; i < SCB; ++i) { boff[i] = tot; tot += bsum[i]; }
    rowptr[NN] = tot;
}

__global__ __launch_bounds__(512) void scan3_kernel(const int* __restrict__ loc,
                                                    const int* __restrict__ boff,
                                                    int* __restrict__ rowptr,
                                                    int* __restrict__ head) {
    const int b = blockIdx.x, t = threadIdx.x;
    const int idx = b * SCH + t;
    if (t < SCH && idx < NN) {
        int r = loc[idx] + boff[b];
        rowptr[idx] = r;
        head[idx] = r;
    }
}

__global__ __launch_bounds__(256) void scatter_kernel(const int* __restrict__ srcs,
                                                      const int* __restrict__ dsts,
                                                      int* __restrict__ head,
                                                      int* __restrict__ perm,
                                                      int* __restrict__ ssrc) {
    int e = blockIdx.x * 256 + threadIdx.x;
    if (e < NE) {
        int d = dsts[e];
        int pos = atomicAdd(&head[d], 1);
        perm[e] = pos;
        ssrc[pos] = srcs[e];
    }
}

// permute edge_attr into dst-sorted order, fp32 -> fp16 (one-time, shared by both layers)
__global__ __launch_bounds__(256) void permute_kernel(const float* __restrict__ ea,
                                                      const int* __restrict__ perm,
                                                      ushort4* __restrict__ easort) {
    const int lane = threadIdx.x & 63, wid = threadIdx.x >> 6;
    const int slot = lane >> 4, hw = lane & 15;
    const int e = (blockIdx.x * 4 + wid) * 4 + slot;
    if (e < NE) {
        const int p = perm[e];
        float4 v = ((const float4*)ea)[(size_t)e * 16 + hw];
        union { _Float16 h[4]; ushort4 u; } pk;
        pk.h[0] = (_Float16)v.x; pk.h[1] = (_Float16)v.y;
        pk.h[2] = (_Float16)v.z; pk.h[3] = (_Float16)v.w;
        easort[(size_t)p * 16 + hw] = pk.u;
    }
}

// fp32 -> fp16 convert (x table for layer-0 gathers), 4 elems/thread
__global__ __launch_bounds__(256) void cvt16_kernel(const float* __restrict__ in,
                                                    _Float16* __restrict__ o) {
    int i = blockIdx.x * 256 + threadIdx.x;   // i indexes groups of 4
    float4 v = ((const float4*)in)[i];
    union { _Float16 h[4]; ushort4 u; } pk;
    pk.h[0] = (_Float16)v.x; pk.h[1] = (_Float16)v.y;
    pk.h[2] = (_Float16)v.z; pk.h[3] = (_Float16)v.w;
    ((ushort4*)o)[i] = pk.u;
}

// ========= fused edge pass: CSR by dst, coalesced fp16 reads + fp16 h gather =========
__global__ __launch_bounds__(256) void edge_agg_kernel(
    const _Float16* __restrict__ h16,    // [NN][64] fp16 gather table
    const ushort4*  __restrict__ easort, // [NE][16] (64 halfs per edge, dst-sorted)
    const float*    __restrict__ W,      // [64][64] W[c][k]
    const float*    __restrict__ bias,   // [64]
    const int*      __restrict__ rowptr,
    const int*      __restrict__ ssrc,   // src per sorted pos
    float*          __restrict__ agg)
{
    __shared__ ushort4 stage[4][64];     // per wave: 4 edges x 64 halfs
    const int lane = threadIdx.x & 63;
    const int wid  = threadIdx.x >> 6;
    const int slot = lane >> 4, hw = lane & 15;

    h2 w2[32];
    {
        const float4* wf = (const float4*)(W + lane * 64);
        #pragma unroll
        for (int k4 = 0; k4 < 16; ++k4) {
            float4 v = wf[k4];
            h2 a; a.x = (_Float16)v.x; a.y = (_Float16)v.y;
            h2 b; b.x = (_Float16)v.z; b.y = (_Float16)v.w;
            w2[2*k4] = a; w2[2*k4+1] = b;
        }
    }
    const float bc = bias[lane];

    const int gw = blockIdx.x * 4 + wid;
    const int nw = gridDim.x * 4;
    for (int n = gw; n < NN; n += nw) {
        const int ofs = rowptr[n];
        const int dg  = rowptr[n + 1] - ofs;
        float acc = 0.f;
        for (int c = 0; c < dg; c += 4) {
            const int rem = dg - c;
            const int pick = slot < rem ? slot : rem - 1;
            const int ssv = ssrc[ofs + c + pick];
            stage[wid][lane] = easort[(size_t)(ofs + c + pick) * 16 + hw];
            if (rem >= 4) {
                float hv[4];
                #pragma unroll
                for (int j = 0; j < 4; ++j) {
                    int sj = __shfl(ssv, j << 4);
                    hv[j] = (float)h16[(size_t)sj * HID + lane];
                }
                asm volatile("s_waitcnt lgkmcnt(0)" ::: "memory");
                #pragma unroll
                for (int j = 0; j < 4; ++j) {
                    const uint4* stu = (const uint4*)&stage[wid][j * 16];
                    float aE = bc;
                    #pragma unroll
                    for (int k = 0; k < 8; ++k) {
                        uint4 u = stu[k];
                        aE = fdot2_(as_h2(u.x), w2[4*k+0], aE);
                        aE = fdot2_(as_h2(u.y), w2[4*k+1], aE);
                        aE = fdot2_(as_h2(u.z), w2[4*k+2], aE);
                        aE = fdot2_(as_h2(u.w), w2[4*k+3], aE);
                    }
                    float m = aE + hv[j];
                    acc += m > 0.f ? m : 0.f;
                }
            } else {
                asm volatile("s_waitcnt lgkmcnt(0)" ::: "memory");
                for (int j = 0; j < rem; ++j) {
                    int sj = __shfl(ssv, j << 4);
                    const uint4* stu = (const uint4*)&stage[wid][j * 16];
                    float aE = bc;
                    #pragma unroll
                    for (int k = 0; k < 8; ++k) {
                        uint4 u = stu[k];
                        aE = fdot2_(as_h2(u.x), w2[4*k+0], aE);
                        aE = fdot2_(as_h2(u.y), w2[4*k+1], aE);
                        aE = fdot2_(as_h2(u.z), w2[4*k+2], aE);
                        aE = fdot2_(as_h2(u.w), w2[4*k+3], aE);
                    }
                    float m = aE + (float)h16[(size_t)sj * HID + lane];
                    acc += m > 0.f ? m : 0.f;
                }
            }
        }
        agg[(size_t)n * HID + lane] = acc;
    }
}

// ---------------- node pass (also emits fp16 copy of h_out for next gather) ----------------
__global__ __launch_bounds__(256) void node_kernel(
    const float* __restrict__ h_in,
    const float* __restrict__ agg,
    const float* __restrict__ W1, const float* __restrict__ b1,
    const float* __restrict__ W2, const float* __restrict__ b2,
    const float* __restrict__ epsp,
    const float* __restrict__ lnS, const float* __restrict__ lnB,
    float*       __restrict__ h_out,
    _Float16*    __restrict__ h16_out)   // may be null
{
    __shared__ float zbuf[4][64];
    __shared__ float tbuf[4][64];
    const int lane = threadIdx.x & 63;
    const int wid  = threadIdx.x >> 6;

    float w1[64], w2[64];
    {
        const float4* wf1 = (const float4*)(W1 + lane * 64);
        const float4* wf2 = (const float4*)(W2 + lane * 64);
        #pragma unroll
        for (int k4 = 0; k4 < 16; ++k4) {
            float4 a = wf1[k4], b = wf2[k4];
            w1[4*k4+0]=a.x; w1[4*k4+1]=a.y; w1[4*k4+2]=a.z; w1[4*k4+3]=a.w;
            w2[4*k4+0]=b.x; w2[4*k4+1]=b.y; w2[4*k4+2]=b.z; w2[4*k4+3]=b.w;
        }
    }
    const float b1c = b1[lane], b2c = b2[lane];
    const float sC = lnS[lane], bC = lnB[lane];
    const float epv = 1.f + epsp[0];

    const int gw = blockIdx.x * 4 + wid;
    const int nw = gridDim.x * 4;
    for (int n = gw; n < NN; n += nw) {
        float z = epv * h_in[(size_t)n*HID + lane] + agg[(size_t)n*HID + lane];
        zbuf[wid][lane] = z;
        asm volatile("s_waitcnt lgkmcnt(0)" ::: "memory");
        float acc = b1c;
        {
            const float4* zf = (const float4*)&zbuf[wid][0];
            #pragma unroll
            for (int k4 = 0; k4 < 16; ++k4) {
                float4 v = zf[k4];
                acc = fmaf(v.x, w1[4*k4+0], acc);
                acc = fmaf(v.y, w1[4*k4+1], acc);
                acc = fmaf(v.z, w1[4*k4+2], acc);
                acc = fmaf(v.w, w1[4*k4+3], acc);
            }
        }
        acc = acc > 0.f ? acc : 0.f;
        tbuf[wid][lane] = acc;
        asm volatile("s_waitcnt lgkmcnt(0)" ::: "memory");
        float acc2 = b2c;
        {
            const float4* tf = (const float4*)&tbuf[wid][0];
            #pragma unroll
            for (int k4 = 0; k4 < 16; ++k4) {
                float4 v = tf[k4];
                acc2 = fmaf(v.x, w2[4*k4+0], acc2);
                acc2 = fmaf(v.y, w2[4*k4+1], acc2);
                acc2 = fmaf(v.z, w2[4*k4+2], acc2);
                acc2 = fmaf(v.w, w2[4*k4+3], acc2);
            }
        }
        float s1 = acc2, s2 = acc2 * acc2;
        #pragma unroll
        for (int off = 32; off >= 1; off >>= 1) {
            s1 += __shfl_xor(s1, off);
            s2 += __shfl_xor(s2, off);
        }
        float mu  = s1 * (1.f/64.f);
        float var = s2 * (1.f/64.f) - mu * mu;
        float r   = rsqrtf(var + 1e-5f);
        float o   = (acc2 - mu) * r * sC + bC;
        float ov  = o > 0.f ? o : 0.f;
        h_out[(size_t)n*HID + lane] = ov;
        if (h16_out) h16_out[(size_t)n*HID + lane] = (_Float16)ov;
    }
}

// ---------------- prep: W2T transpose + selp = b_ih + sel @ W_ih[:, :64]^T ----------------
// outputs stored PERMUTED to lstm thread order: thread t <- gate (t&3)*128 + (t>>2)
__global__ __launch_bounds__(512) void prep_kernel(
    const float* __restrict__ Wih,   // [512][96]
    const float* __restrict__ bih,   // [512]
    const float* __restrict__ h2v,   // [NN][64]
    const int*   __restrict__ nidx,  // [64]
    float*       __restrict__ W2T,   // [32][512] permuted cols
    float*       __restrict__ selp)  // [64][512] permuted cols
{
    const int g = threadIdx.x;                        // gate index 0..511
    const int pos = ((g & 127) << 2) | (g >> 7);      // lstm thread owning gate g
    if (blockIdx.x == BB) {
        #pragma unroll
        for (int k = 0; k < 32; ++k)
            W2T[k * G4 + pos] = Wih[g * 96 + 64 + k];
    } else {
        const int b = blockIdx.x;
        __shared__ float hrow[64];
        if (g < 64) hrow[g] = h2v[(size_t)nidx[b] * HID + g];
        __syncthreads();
        float acc = bih[g];
        #pragma unroll
        for (int k = 0; k < 64; ++k)
            acc = fmaf(hrow[k], Wih[g * 96 + k], acc);
        selp[b * G4 + pos] = acc;
    }
}

// ---------------- xp[t][b][tid] = selp[b][tid] + x_seq[b][t] @ W2T[:,tid] ----------------
__global__ __launch_bounds__(512) void xp_kernel(
    const float* __restrict__ xseq,  // [B][T][32]
    const float* __restrict__ selp,  // [B][512] permuted
    const float* __restrict__ W2T,   // [32][512] permuted
    float*       __restrict__ xp)    // [T][B][512] permuted
{
    const int g   = threadIdx.x;
    const int row = blockIdx.x;      // row = t*64 + b
    const int t   = row >> 6;
    const int b   = row & 63;
    __shared__ float xs[32];
    if (g < 32) xs[g] = xseq[((size_t)b * TT + t) * 32 + g];
    __syncthreads();
    float acc = selp[b * G4 + g];
    #pragma unroll
    for (int k = 0; k < 32; ++k)
        acc = fmaf(xs[k], W2T[k * G4 + g], acc);
    xp[(size_t)row * G4 + g] = acc;
}

// ---------------- LSTM recurrence + final LN + fc ----------------
// 64 blocks x 512 thr (1 row/block, 8 waves). Per step the h-vector (64 packed
// fp16 pairs) is read with ONE coalesced ds_read_b32 per wave, then broadcast
// lane-by-lane via v_readlane (VALU) feeding fdot2 — DS-pipe cost per step
// drops from ~128 ds_read_b128 to ~16 small DS ops. Gate exchange via DPP
// quad_perm (VALU). One barrier/step, double-buffered h.
__global__ __launch_bounds__(512) void lstm_kernel(
    const float* __restrict__ xp,    // [T][B][512] thread-order
    const float* __restrict__ Whh,   // [512][128]
    const float* __restrict__ bhh,   // [512]
    const float* __restrict__ lnS, const float* __restrict__ lnB,  // [128]
    const float* __restrict__ fcW,   // [1][128]
    const float* __restrict__ fcb,   // [1]
    float*       __restrict__ out)   // [64]
{
    const int t    = threadIdx.x;
    const int b    = blockIdx.x;
    const int lane = t & 63;
    const int gt   = t & 3;
    const int j    = t >> 2;
    const int gate = gt * LH + j;

    // Whh row 'gate' packed fp16 -> 64 VGPRs; w2[k] multiplies h-pair k
    h2 w2[64];
    {
        const float4* wf = (const float4*)(Whh + (size_t)gate * LH);
        #pragma unroll
        for (int k4 = 0; k4 < 32; ++k4) {
            float4 v = wf[k4];
            h2 a; a.x = (_Float16)v.x; a.y = (_Float16)v.y;
            h2 c2; c2.x = (_Float16)v.z; c2.y = (_Float16)v.w;
            w2[2*k4] = a; w2[2*k4+1] = c2;
        }
    }
    const float bg = bhh[gate];
    const float s_ = (gt == 2) ? 2.f : 1.f;
    const float a_ = (gt == 2) ? 2.f : 1.f;
    const float d_ = (gt == 2) ? -1.f : 0.f;

    __shared__ _Float16 hb[2][LH];        // packed h halves, double buffered
    __shared__ float h_final[LH];
    if (t < 64) ((unsigned int*)&hb[0][0])[t] = 0u;
    float c = 0.f;
    float h_last = 0.f;
    __syncthreads();

    float xv = xp[(size_t)b * G4 + t];    // t=0 slice

    auto step = [&](const _Float16* hbR, _Float16* hbW, int ts) {
        const int tn = (ts + 1 < TT) ? ts + 1 : ts;
        const float xv_next = xp[((size_t)tn * BB + b) * G4 + t];

        // one coalesced b32 read per wave: lane l holds h-pair l
        unsigned int hreg = ((const unsigned int*)hbR)[lane];

        float a0 = 0.f, a1 = 0.f, a2 = 0.f, a3 = 0.f;
        #pragma unroll
        for (int k = 0; k < 64; k += 4) {
            int s0 = __builtin_amdgcn_readlane((int)hreg, k + 0);
            int s1 = __builtin_amdgcn_readlane((int)hreg, k + 1);
            int s2 = __builtin_amdgcn_readlane((int)hreg, k + 2);
            int s3 = __builtin_amdgcn_readlane((int)hreg, k + 3);
            a0 = fdot2_(as_h2((unsigned int)s0), w2[k + 0], a0);
            a1 = fdot2_(as_h2((unsigned int)s1), w2[k + 1], a1);
            a2 = fdot2_(as_h2((unsigned int)s2), w2[k + 2], a2);
            a3 = fdot2_(as_h2((unsigned int)s3), w2[k + 3], a3);
        }
        float acc = xv + bg + ((a0 + a1) + (a2 + a3));

        // branch-free activation (sigmoid for i/f/o; tanh = 2*sig(2x)-1 for g)
        float act = fmaf(a_, __fdividef(1.f, 1.f + __expf(-s_ * acc)), d_);

        // quad exchange via DPP: gate q's value sits in v[q ^ gt]
        float v0 = act;
        float v1 = dpp_mov<0xB1>(v0);     // lane^1
        float v2 = dpp_mov<0x4E>(v0);     // lane^2
        float v3 = dpp_mov<0x4E>(v1);     // lane^3
        float iv = (gt==0)?v0:(gt==1)?v1:(gt==2)?v2:v3;
        float fv = (gt==1)?v0:(gt==0)?v1:(gt==3)?v2:v3;
        float gv = (gt==2)?v0:(gt==3)?v1:(gt==0)?v2:v3;
        float ov = (gt==3)?v0:(gt==2)?v1:(gt==1)?v2:v3;

        c = fmaf(fv, c, iv * gv);
        h_last = ov * tanh_fast(c);

        if (gt == 0) hbW[j] = (_Float16)h_last;   // one ds_write_b16 per wave
        __syncthreads();

        xv = xv_next;
    };

    for (int ts = 0; ts < TT; ts += 2) {
        step(&hb[0][0], &hb[1][0], ts);
        step(&hb[1][0], &hb[0][0], ts + 1);
    }

    // epilogue: stash fp32 h once, then layernorm over h (128) + fc -> out[b]
    if (gt == 0) h_final[j] = h_last;
    __syncthreads();
    if (t < 64) {
        float h0 = h_final[t], h1 = h_final[t + 64];
        float s1 = h0 + h1, s2 = h0*h0 + h1*h1;
        #pragma unroll
        for (int off = 32; off >= 1; off >>= 1) {
            s1 += __shfl_xor(s1, off);
            s2 += __shfl_xor(s2, off);
        }
        float mu  = s1 * (1.f/128.f);
        float var = s2 * (1.f/128.f) - mu * mu;
        float rr  = rsqrtf(var + 1e-5f);
        float p = ((h0 - mu)*rr*lnS[t]      + lnB[t])      * fcW[t]
                + ((h1 - mu)*rr*lnS[t + 64] + lnB[t + 64]) * fcW[t + 64];
        #pragma unroll
        for (int off = 32; off >= 1; off >>= 1) p += __shfl_xor(p, off);
        if (t == 0) out[b] = p + fcb[0];
    }
}

extern "C" void kernel_launch(void* const* d_in, const int* in_sizes, int n_in,
                              void* d_out, int out_size, void* d_ws, size_t ws_size,
                              hipStream_t stream) {
    const float* x     = (const float*)d_in[0];
    const float* ea    = (const float*)d_in[1];
    const float* xseq  = (const float*)d_in[2];
    const float* linW  = (const float*)d_in[3];
    const float* linB  = (const float*)d_in[4];
    const float* mW1   = (const float*)d_in[5];
    const float* mb1   = (const float*)d_in[6];
    const float* mW2   = (const float*)d_in[7];
    const float* mb2   = (const float*)d_in[8];
    const float* eps   = (const float*)d_in[9];
    const float* lnS   = (const float*)d_in[10];
    const float* lnB   = (const float*)d_in[11];
    const float* Wih   = (const float*)d_in[12];
    const float* Whh   = (const float*)d_in[13];
    const float* bih   = (const float*)d_in[14];
    const float* bhh   = (const float*)d_in[15];
    const float* llnS  = (const float*)d_in[16];
    const float* llnB  = (const float*)d_in[17];
    const float* fcW   = (const float*)d_in[18];
    const float* fcb   = (const float*)d_in[19];
    const int*   eidx  = (const int*)d_in[20];
    const int*   nidx  = (const int*)d_in[21];
    float* out = (float*)d_out;

    const int* srcs = eidx;
    const int* dsts = eidx + NE;

    // workspace layout
    float* ws   = (float*)d_ws;
    float* agg  = ws;                              // NN*64
    float* h1   = agg  + (size_t)NN * HID;
    float* h2m  = h1   + (size_t)NN * HID;
    float* selp = h2m  + (size_t)NN * HID;         // BB*G4
    float* W2T  = selp + (size_t)BB * G4;          // 32*G4
    float* xp   = W2T  + (size_t)32 * G4;          // TT*BB*G4
    int*   deg    = (int*)(xp + (size_t)TT * BB * G4);  // NN
    int*   rowptr = deg + NN;                      // NN+1
    int*   head   = rowptr + NN + 2;               // NN
    int*   loc    = head + NN;                     // NN
    int*   bsum   = loc + NN;                      // SCB
    int*   boff   = bsum + SCB + 3;                // SCB
    int*   perm   = boff + SCB + 3;                // NE
    int*   ssrc   = perm + NE;                     // NE
    uintptr_t ep = (uintptr_t)(ssrc + NE);
    ep = (ep + 15) & ~(uintptr_t)15;
    ushort4* easort = (ushort4*)ep;                // NE*16 ushort4 = 102.4 MB
    _Float16* x16   = (_Float16*)(easort + (size_t)NE * 16);  // NN*64 halfs
    _Float16* h1_16 = x16 + (size_t)NN * HID;                 // NN*64 halfs

    // ---- CSR build + ea permute + x fp16 (shared by both layers) ----
    hipMemsetAsync(deg, 0, (size_t)NN * sizeof(int), stream);
    hist_kernel<<<(NE + 255) / 256, 256, 0, stream>>>(dsts, deg);
    scan1_kernel<<<SCB, 512, 0, stream>>>(deg, loc, bsum);
    scan2_kernel<<<1, 1, 0, stream>>>(bsum, boff, rowptr);
    scan3_kernel<<<SCB, 512, 0, stream>>>(loc, boff, rowptr, head);
    scatter_kernel<<<(NE + 255) / 256, 256, 0, stream>>>(srcs, dsts, head, perm, ssrc);
    permute_kernel<<<NE / 16, 256, 0, stream>>>(ea, perm, easort);
    cvt16_kernel<<<(NN * HID / 4 + 255) / 256, 256, 0, stream>>>(x, x16);

    // ---- layer 0 ----
    edge_agg_kernel<<<2048, 256, 0, stream>>>(x16, easort, linW, linB, rowptr, ssrc, agg);
    node_kernel<<<512, 256, 0, stream>>>(x, agg, mW1, mb1, mW2, mb2, eps, lnS, lnB, h1, h1_16);
    // ---- layer 1 ----
    edge_agg_kernel<<<2048, 256, 0, stream>>>(h1_16, easort, linW + 64*64, linB + 64, rowptr, ssrc, agg);
    node_kernel<<<512, 256, 0, stream>>>(h1, agg, mW1 + 64*64, mb1 + 64, mW2 + 64*64, mb2 + 64,
                                         eps + 1, lnS + 64, lnB + 64, h2m, (_Float16*)nullptr);
    // ---- LSTM input projection (permuted to lstm thread order) ----
    prep_kernel<<<BB + 1, 512, 0, stream>>>(Wih, bih, h2m, nidx, W2T, selp);
    xp_kernel<<<TT * BB, 512, 0, stream>>>(xseq, selp, W2T, xp);
    // ---- LSTM recurrence + head (1 row/block, readlane broadcast) ----
    lstm_kernel<<<BB, 512, 0, stream>>>(xp, Whh, bhh, llnS, llnB, fcW, fcb, out);
}